// Round 16
// baseline (192.154 us; speedup 1.0000x reference)
//
#include <hip/hip_runtime.h>

typedef __attribute__((ext_vector_type(4))) float f32x4;
typedef __attribute__((ext_vector_type(8))) short s16x8;

struct alignas(8) us4 { ushort x, y, z, w; };

__device__ __forceinline__ ushort f2bf(float f) {
  unsigned u = __builtin_bit_cast(unsigned, f);
  u += 0x7fffu + ((u >> 16) & 1u);
  return (ushort)(u >> 16);
}
__device__ __forceinline__ float bf2f(ushort h) {
  unsigned u = ((unsigned)h) << 16;
  return __builtin_bit_cast(float, u);
}

__device__ __forceinline__ void gload_lds16(const ushort* g, ushort* l) {
  __builtin_amdgcn_global_load_lds((const __attribute__((address_space(1))) unsigned int*)g,
                                   (__attribute__((address_space(3))) unsigned int*)l, 16, 0, 0);
}

// ---------------- merged preprocessing: cast + 4 weight transposes + rope tables --
__global__ __launch_bounds__(256) void preproc_kernel(
    const float* __restrict__ x, const float* __restrict__ Wq, const float* __restrict__ Wk,
    const float* __restrict__ Wv, const float* __restrict__ Wo,
    ushort* __restrict__ xb, ushort* __restrict__ WqkvT, ushort* __restrict__ WoT,
    float* __restrict__ rc, float* __restrict__ rs) {
  __shared__ float tile[32][33];
  int bid = blockIdx.x, tid = threadIdx.x;
  if (bid < 2048) {
    const int n4 = 4096 * 2048 / 4;
    for (int i = bid * 256 + tid; i < n4; i += 2048 * 256) {
      float4 v = reinterpret_cast<const float4*>(x)[i];
      us4 o;
      o.x = f2bf(v.x); o.y = f2bf(v.y); o.z = f2bf(v.z); o.w = f2bf(v.w);
      reinterpret_cast<us4*>(xb)[i] = o;
    }
  } else if (bid < 2560) {
    int t = (bid - 2048) * 4 + (tid >> 6), j = tid & 63;
    float inv = expf(-(float)j * (9.210340371976184f / 64.0f));
    float ang = (float)t * inv;
    float s, c;
    sincosf(ang, &s, &c);
    rc[t * 64 + j] = c;
    rs[t * 64 + j] = s;
  } else {
    int wid = bid - 2560;
    const float* src;
    ushort* dst;
    int C, bx, by;
    if (wid < 4096) { src = Wq; dst = WqkvT; C = 2048; bx = wid & 63; by = wid >> 6; }
    else if (wid < 5120) { int w2 = wid - 4096; src = Wk; dst = WqkvT + (size_t)2048 * 2048; C = 512; bx = w2 & 15; by = w2 >> 4; }
    else if (wid < 6144) { int w2 = wid - 5120; src = Wv; dst = WqkvT + (size_t)2560 * 2048; C = 512; bx = w2 & 15; by = w2 >> 4; }
    else { int w2 = wid - 6144; src = Wo; dst = WoT; C = 2048; bx = w2 & 63; by = w2 >> 6; }
    int c0 = bx * 32, r0 = by * 32;
    int tx = tid & 31, ty = tid >> 5;
#pragma unroll
    for (int i = 0; i < 4; ++i)
      tile[ty + i * 8][tx] = src[(size_t)(r0 + ty + i * 8) * C + c0 + tx];
    __syncthreads();
#pragma unroll
    for (int i = 0; i < 4; ++i)
      dst[(size_t)(c0 + ty + i * 8) * 2048 + r0 + tx] = f2bf(tile[tx][ty + i * 8]);
  }
}

// ---------------- merged post-QKV: K RMSNorm+RoPE and V transpose ----------------
__global__ __launch_bounds__(256) void postqkv_kernel(
    const ushort* __restrict__ qkv, const float* __restrict__ kw,
    ushort* __restrict__ Kb, ushort* __restrict__ vt,
    const float* __restrict__ rc, const float* __restrict__ rs) {
  __shared__ ushort tile[64][136];
  int bid = blockIdx.x, tid = threadIdx.x;
  if (bid < 4096) {
    int wv = tid >> 6, lane = tid & 63;
    int row = bid * 4 + wv;
    int token = row >> 2, head = row & 3;
    const ushort* p = qkv + (size_t)token * 3072 + 2048 + head * 128;
    float x1 = bf2f(p[lane]), x2 = bf2f(p[lane + 64]);
    float ss = x1 * x1 + x2 * x2;
#pragma unroll
    for (int m = 32; m > 0; m >>= 1) ss += __shfl_xor(ss, m);
    float r = rsqrtf(ss * (1.0f / 128.0f) + 1e-6f);
    float xn1 = x1 * r * kw[lane], xn2 = x2 * r * kw[lane + 64];
    int t = token & 2047;
    float c = rc[t * 64 + lane], s = rs[t * 64 + lane];
    ushort* o = Kb + (size_t)token * 512 + head * 128;
    o[lane] = f2bf(xn1 * c - xn2 * s);
    o[lane + 64] = f2bf(xn2 * c + xn1 * s);
  } else {
    int bx = bid - 4096;
    int st = bx & 31, kvh = (bx >> 5) & 3, b = bx >> 7;
    int s0 = st * 64;
#pragma unroll
    for (int p = 0; p < 4; ++p) {
      int idx = p * 2048 + tid * 8;
      int s = idx >> 7, d = idx & 127;
      *(s16x8*)&tile[s][d] =
          *(const s16x8*)&qkv[(size_t)(b * 2048 + s0 + s) * 3072 + 2560 + kvh * 128 + d];
    }
    __syncthreads();
#pragma unroll
    for (int p = 0; p < 4; ++p) {
      int idx = p * 2048 + tid * 8;
      int d = idx >> 6, s = idx & 63;
      s16x8 v;
#pragma unroll
      for (int u = 0; u < 8; ++u) v[u] = (short)tile[s + u][d];
      *(s16x8*)&vt[(size_t)((b * 4 + kvh) * 128 + d) * 2048 + s0 + s] = v;
    }
  }
}

// ---------------- bf16 MFMA GEMM, 256x192 tile, 2-slot dbuf, SINGLE barrier/tile --
// T3-minimum schedule (guide §5.5): stage(t+1) -> ds_read+MFMA(t) -> vmcnt(0)
// -> barrier. The one barrier certifies (i) tile t+1 resident (all waves
// drained own loads pre-barrier) and (ii) slot t free for reuse. Drain is
// covered by the 48-MFMA compute phase. 16x16 = 256 blocks = one residency
// round. 8 waves (2M x 4N), wave tile 128x48.
template <bool OUTF32>
__global__ __launch_bounds__(512, 1) void gemm192_kernel(const ushort* __restrict__ A,
                                                         const ushort* __restrict__ Bt,
                                                         void* __restrict__ Cp,
                                                         int M, int N, int K) {
  __shared__ ushort As[2][256][64];  // 64 KB
  __shared__ ushort Bs[2][192][64];  // 48 KB
  int tid = threadIdx.x;
  int lane = tid & 63, wv = tid >> 6;  // 8 waves
  int wm = wv >> 2, wn = wv & 3;       // 2 x 4
  int lr = lane & 15, lg = lane >> 4;
  int nwg = gridDim.x * gridDim.y;
  int flat = blockIdx.y * gridDim.x + blockIdx.x;
  int swz = (flat & 7) * (nwg >> 3) + (flat >> 3);
  int bx = swz % gridDim.x, by = swz / gridDim.x;
  int m0 = by * 256, n0 = bx * 192;
  int srow8 = lane >> 3;
  int gcol = ((lane & 7) * 8) ^ (srow8 << 3);
  int nt = K >> 6;

  const ushort* Abase = A + (size_t)m0 * K;
  const ushort* Bbase = Bt + (size_t)n0 * K;

  auto stage = [&](int slot, int t) {
#pragma unroll
    for (int p = 0; p < 4; ++p) {
      int r0 = wv * 32 + p * 8;
      gload_lds16(&Abase[(size_t)(r0 + srow8) * K + t * 64 + gcol], &As[slot][r0][0]);
    }
#pragma unroll
    for (int p = 0; p < 3; ++p) {
      int r0 = wv * 24 + p * 8;
      gload_lds16(&Bbase[(size_t)(r0 + srow8) * K + t * 64 + gcol], &Bs[slot][r0][0]);
    }
  };

  // prologue: tile 0 staged and certified resident
  stage(0, 0);
  asm volatile("s_waitcnt vmcnt(0)" ::: "memory");
  __builtin_amdgcn_s_barrier();

  f32x4 acc[8][3] = {};
  int arow[8], aswz[8], brow[3], bswz[3];
#pragma unroll
  for (int i = 0; i < 8; ++i) {
    arow[i] = wm * 128 + i * 16 + lr;
    aswz[i] = (arow[i] & 7) << 3;
  }
#pragma unroll
  for (int j = 0; j < 3; ++j) {
    brow[j] = wn * 48 + j * 16 + lr;
    bswz[j] = (brow[j] & 7) << 3;
  }

  for (int t = 0; t < nt; ++t) {
    int c = t & 1;
    bool pf = (t + 1) < nt;
    if (pf) stage(c ^ 1, t + 1);   // issue next-tile loads into the other slot
#pragma unroll
    for (int ks = 0; ks < 2; ++ks) {
      s16x8 a[8], b[3];
#pragma unroll
      for (int i = 0; i < 8; ++i)
        a[i] = *(const s16x8*)&As[c][arow[i]][(ks * 32 + lg * 8) ^ aswz[i]];
#pragma unroll
      for (int j = 0; j < 3; ++j)
        b[j] = *(const s16x8*)&Bs[c][brow[j]][(ks * 32 + lg * 8) ^ bswz[j]];
      __builtin_amdgcn_s_setprio(1);
#pragma unroll
      for (int i = 0; i < 8; ++i)
#pragma unroll
        for (int j = 0; j < 3; ++j)
          acc[i][j] = __builtin_amdgcn_mfma_f32_16x16x32_bf16(a[i], b[j], acc[i][j], 0, 0, 0);
      __builtin_amdgcn_s_setprio(0);
    }
    if (pf) {
      asm volatile("s_waitcnt vmcnt(0)" ::: "memory");  // t+1 drained (covered by MFMA)
      __builtin_amdgcn_s_barrier();                     // joint certify: data in + slot free
    }
  }
#pragma unroll
  for (int i = 0; i < 8; ++i)
#pragma unroll
    for (int j = 0; j < 3; ++j) {
      int row = m0 + wm * 128 + i * 16 + lg * 4;
      int col = n0 + wn * 48 + j * 16 + lr;
#pragma unroll
      for (int r = 0; r < 4; ++r) {
        float v = acc[i][j][r];
        if (OUTF32)
          reinterpret_cast<float*>(Cp)[(size_t)(row + r) * N + col] = v;
        else
          reinterpret_cast<ushort*>(Cp)[(size_t)(row + r) * N + col] = f2bf(v);
      }
    }
}

// ---------------- bf16 MFMA GEMM, 256x128 tile, 3-slot pipelined (proj) ----------
template <bool OUTF32>
__global__ __launch_bounds__(512, 2) void gemm256_kernel(const ushort* __restrict__ A,
                                                         const ushort* __restrict__ Bt,
                                                         void* __restrict__ Cp,
                                                         int M, int N, int K) {
  __shared__ ushort As[3][256][64];  // 96 KB
  __shared__ ushort Bs[3][128][64];  // 48 KB
  int tid = threadIdx.x;
  int lane = tid & 63, wv = tid >> 6;  // 8 waves
  int wm = wv >> 1, wn = wv & 1;       // 4 x 2
  int lr = lane & 15, lg = lane >> 4;
  int nwg = gridDim.x * gridDim.y;
  int flat = blockIdx.y * gridDim.x + blockIdx.x;
  int swz = (flat & 7) * (nwg >> 3) + (flat >> 3);
  int bx = swz % gridDim.x, by = swz / gridDim.x;
  int m0 = by * 256, n0 = bx * 128;
  int srow8 = lane >> 3;
  int gcol = ((lane & 7) * 8) ^ (srow8 << 3);
  int nt = K >> 6;

  const ushort* Abase = A + (size_t)m0 * K;
  const ushort* Bbase = Bt + (size_t)n0 * K;

  auto stageA = [&](int slot, int t, int p) {
    int r0 = (wv * 4 + p) * 8;
    gload_lds16(&Abase[(size_t)(r0 + srow8) * K + t * 64 + gcol], &As[slot][r0][0]);
  };
  auto stageB = [&](int slot, int t, int p) {
    int r0 = (wv * 2 + p) * 8;
    gload_lds16(&Bbase[(size_t)(r0 + srow8) * K + t * 64 + gcol], &Bs[slot][r0][0]);
  };

  stageA(0, 0, 0); stageA(0, 0, 1); stageB(0, 0, 0);
  stageA(0, 0, 2); stageA(0, 0, 3); stageB(0, 0, 1);
  stageA(1, 1, 0); stageA(1, 1, 1); stageB(1, 1, 0);
  stageA(1, 1, 2); stageA(1, 1, 3); stageB(1, 1, 1);

  f32x4 acc[4][4] = {};
  int arow[4], brow[4], aswz[4], bswz[4];
#pragma unroll
  for (int i = 0; i < 4; ++i) {
    arow[i] = wm * 64 + i * 16 + lr;
    aswz[i] = (arow[i] & 7) << 3;
    brow[i] = wn * 64 + i * 16 + lr;
    bswz[i] = (brow[i] & 7) << 3;
  }

  for (int t = 0; t < nt; ++t) {
    int cur = t % 3, pf = (t + 2) % 3;
    if (t + 1 < nt) {
      asm volatile("s_waitcnt vmcnt(6)" ::: "memory");
    } else {
      asm volatile("s_waitcnt vmcnt(0)" ::: "memory");
    }
    __builtin_amdgcn_s_barrier();
    bool do_pf = (t + 2) < nt;
    {
      s16x8 a[4], b[4];
#pragma unroll
      for (int i = 0; i < 4; ++i) a[i] = *(const s16x8*)&As[cur][arow[i]][(lg * 8) ^ aswz[i]];
#pragma unroll
      for (int j = 0; j < 4; ++j) b[j] = *(const s16x8*)&Bs[cur][brow[j]][(lg * 8) ^ bswz[j]];
      if (do_pf) { stageA(pf, t + 2, 0); stageA(pf, t + 2, 1); stageB(pf, t + 2, 0); }
      __builtin_amdgcn_s_setprio(1);
#pragma unroll
      for (int i = 0; i < 4; ++i)
#pragma unroll
        for (int j = 0; j < 4; ++j)
          acc[i][j] = __builtin_amdgcn_mfma_f32_16x16x32_bf16(a[i], b[j], acc[i][j], 0, 0, 0);
      __builtin_amdgcn_s_setprio(0);
    }
    {
      s16x8 a[4], b[4];
#pragma unroll
      for (int i = 0; i < 4; ++i) a[i] = *(const s16x8*)&As[cur][arow[i]][(32 + lg * 8) ^ aswz[i]];
#pragma unroll
      for (int j = 0; j < 4; ++j) b[j] = *(const s16x8*)&Bs[cur][brow[j]][(32 + lg * 8) ^ bswz[j]];
      if (do_pf) { stageA(pf, t + 2, 2); stageA(pf, t + 2, 3); stageB(pf, t + 2, 1); }
      __builtin_amdgcn_s_setprio(1);
#pragma unroll
      for (int i = 0; i < 4; ++i)
#pragma unroll
        for (int j = 0; j < 4; ++j)
          acc[i][j] = __builtin_amdgcn_mfma_f32_16x16x32_bf16(a[i], b[j], acc[i][j], 0, 0, 0);
      __builtin_amdgcn_s_setprio(0);
    }
  }
#pragma unroll
  for (int i = 0; i < 4; ++i)
#pragma unroll
    for (int j = 0; j < 4; ++j) {
      int row = m0 + wm * 64 + i * 16 + lg * 4;
      int col = n0 + wn * 64 + j * 16 + lr;
#pragma unroll
      for (int r = 0; r < 4; ++r) {
        float v = acc[i][j][r];
        if (OUTF32)
          reinterpret_cast<float*>(Cp)[(size_t)(row + r) * N + col] = v;
        else
          reinterpret_cast<ushort*>(Cp)[(size_t)(row + r) * N + col] = f2bf(v);
      }
    }
}

// ---------------- causal GQA flash attention (r9 proven) ----------------
__global__ __launch_bounds__(256, 2) void attn_kernel(const ushort* __restrict__ QKV,
                                                      const ushort* __restrict__ Kn,
                                                      const ushort* __restrict__ Vt,
                                                      ushort* __restrict__ AO,
                                                      const float* __restrict__ rc,
                                                      const float* __restrict__ rs,
                                                      const float* __restrict__ qw) {
  __shared__ ushort Ks[2][64][128];   // 32 KB
  __shared__ ushort Vs[2][128][64];   // 32 KB
  __shared__ ushort Ps[4][32][64];    // 16 KB
  int bxi = blockIdx.x;
  int g = bxi >> 5, bh = bxi & 31;
  int qt = (g < 8) ? (15 - g) : (g - 8);  // pair long+short on each CU
  int b = bh >> 4, h = bh & 15, kvh = h >> 2;
  int q0 = qt * 128;
  int nt = 2 * qt + 2;
  int tid = threadIdx.x, lane = tid & 63, w = tid >> 6;
  int lr = lane & 15, lg = lane >> 4;

  int ksrow = lane >> 4, kscol = (lane & 15) * 8;
  int vsrow = lane >> 3, vscol = (lane & 7) * 8;

  auto stage = [&](int c, int t) {
    int p0 = t * 64;
#pragma unroll
    for (int p = 0; p < 4; ++p) {
      int r0 = w * 16 + p * 4;
      int row = r0 + ksrow;
      int gc = kscol ^ ((row & 7) << 3);
      gload_lds16(&Kn[(size_t)(b * 2048 + p0 + row) * 512 + kvh * 128 + gc], &Ks[c][r0][0]);
    }
#pragma unroll
    for (int p = 0; p < 4; ++p) {
      int r0 = w * 32 + p * 8;
      int row = r0 + vsrow;
      int gc = vscol ^ ((row & 7) << 3);
      gload_lds16(&Vt[(size_t)((b * 4 + kvh) * 128 + row) * 2048 + p0 + gc], &Vs[c][r0][0]);
    }
  };

  stage(0, 0);  // tile 0 in flight — overlaps the Q-build below

  // ---- Q build: inline RMSNorm + RoPE + QSCALE ----
  const float QSCALE = 0.12751744f;  // log2e / sqrt(128)
  s16x8 qf[2][4];
#pragma unroll
  for (int qa = 0; qa < 2; ++qa) {
    int t_tok = q0 + w * 32 + qa * 16 + lr;
    const ushort* qp = QKV + (size_t)(b * 2048 + t_tok) * 3072 + h * 128;
    float xv[4][8];
    float ss = 0.f;
#pragma unroll
    for (int ks = 0; ks < 4; ++ks) {
      s16x8 raw = *(const s16x8*)&qp[ks * 32 + lg * 8];
#pragma unroll
      for (int j = 0; j < 8; ++j) {
        float x = bf2f((ushort)raw[j]);
        xv[ks][j] = x;
        ss += x * x;
      }
    }
    ss += __shfl_xor(ss, 16);
    ss += __shfl_xor(ss, 32);
    float rms = rsqrtf(ss * (1.0f / 128.0f) + 1e-6f);
#pragma unroll
    for (int ks = 0; ks < 2; ++ks) {
      int dbase = ks * 32 + lg * 8;
      float cc[8], sn[8], w1[8], w2[8];
      *(float4*)&cc[0] = *(const float4*)&rc[(size_t)t_tok * 64 + dbase];
      *(float4*)&cc[4] = *(const float4*)&rc[(size_t)t_tok * 64 + dbase + 4];
      *(float4*)&sn[0] = *(const float4*)&rs[(size_t)t_tok * 64 + dbase];
      *(float4*)&sn[4] = *(const float4*)&rs[(size_t)t_tok * 64 + dbase + 4];
      *(float4*)&w1[0] = *(const float4*)&qw[dbase];
      *(float4*)&w1[4] = *(const float4*)&qw[dbase + 4];
      *(float4*)&w2[0] = *(const float4*)&qw[dbase + 64];
      *(float4*)&w2[4] = *(const float4*)&qw[dbase + 68];
      s16x8 o1, o2;
#pragma unroll
      for (int j = 0; j < 8; ++j) {
        float x1 = xv[ks][j] * rms * w1[j];
        float x2 = xv[ks + 2][j] * rms * w2[j];
        o1[j] = (short)f2bf((x1 * cc[j] - x2 * sn[j]) * QSCALE);
        o2[j] = (short)f2bf((x2 * cc[j] + x1 * sn[j]) * QSCALE);
      }
      qf[qa][ks] = o1;
      qf[qa][ks + 2] = o2;
    }
  }

  f32x4 O[2][8] = {};
  float mrow[2] = {-1e30f, -1e30f};  // wave-row-uniform running max (log2 domain)
  float lrow[2] = {0.f, 0.f};        // per-lane partial sum over this lane's k-slice

  for (int t = 0; t < nt; ++t) {
    int c = t & 1;
    if (t + 1 < nt) {
      stage(c ^ 1, t + 1);                               // prefetch next tile
      asm volatile("s_waitcnt vmcnt(8)" ::: "memory");   // tile t's 8 loads done
    } else {
      asm volatile("s_waitcnt vmcnt(0)" ::: "memory");
    }
    __builtin_amdgcn_s_barrier();                        // (a) tile t visible

    bool skip = (t == 2 * qt + 1) && (w < 2);            // fully-masked wave-tile
    if (!skip) {
      // SWAPPED: sacc[qa][fp] = S^T tile: lane holds q=lane&15, k=fp*16+lg*4+r
      f32x4 sacc[2][4] = {};
      __builtin_amdgcn_s_setprio(1);
#pragma unroll
      for (int ks = 0; ks < 4; ++ks) {
        s16x8 bk[4];
#pragma unroll
        for (int fp = 0; fp < 4; ++fp) {
          int kr = fp * 16 + lr;
          bk[fp] = *(const s16x8*)&Ks[c][kr][(ks * 32 + lg * 8) ^ ((kr & 7) << 3)];
        }
#pragma unroll
        for (int qa = 0; qa < 2; ++qa)
#pragma unroll
          for (int fp = 0; fp < 4; ++fp)
            sacc[qa][fp] = __builtin_amdgcn_mfma_f32_16x16x32_bf16(bk[fp], qf[qa][ks], sacc[qa][fp], 0, 0, 0);
      }
      __builtin_amdgcn_s_setprio(0);

      // causal mask (only tiles straddling the diagonal)
      if (t >= 2 * qt) {
        int p0 = t * 64;
#pragma unroll
        for (int qa = 0; qa < 2; ++qa)
#pragma unroll
          for (int fp = 0; fp < 4; ++fp)
#pragma unroll
            for (int r = 0; r < 4; ++r) {
              int qg = q0 + w * 32 + qa * 16 + lr;
              int pg = p0 + fp * 16 + lg * 4 + r;
              if (pg > qg) sacc[qa][fp][r] = -1e30f;
            }
      }

      // in-lane row max (16 values, tree)
      float pml[2];
#pragma unroll
      for (int qa = 0; qa < 2; ++qa) {
        float m0 = fmaxf(fmaxf(sacc[qa][0][0], sacc[qa][0][1]), fmaxf(sacc[qa][0][2], sacc[qa][0][3]));
        float m1 = fmaxf(fmaxf(sacc[qa][1][0], sacc[qa][1][1]), fmaxf(sacc[qa][1][2], sacc[qa][1][3]));
        float m2 = fmaxf(fmaxf(sacc[qa][2][0], sacc[qa][2][1]), fmaxf(sacc[qa][2][2], sacc[qa][2][3]));
        float m3 = fmaxf(fmaxf(sacc[qa][3][0], sacc[qa][3][1]), fmaxf(sacc[qa][3][2], sacc[qa][3][3]));
        pml[qa] = fmaxf(fmaxf(m0, m1), fmaxf(m2, m3));
      }
      // defer gate on in-lane max: pm_full > thr  <=>  any lane's pml > thr
      bool need = (pml[0] > mrow[0] + 8.0f) | (pml[1] > mrow[1] + 8.0f);
      if (__any((int)need)) {
        float fsc[2];
#pragma unroll
        for (int qa = 0; qa < 2; ++qa) {
          float pm = fmaxf(pml[qa], __shfl_xor(pml[qa], 16));
          pm = fmaxf(pm, __shfl_xor(pm, 32));
          float mn = fmaxf(mrow[qa], pm);
          fsc[qa] = __builtin_amdgcn_exp2f(mrow[qa] - mn);
          mrow[qa] = mn;
          lrow[qa] *= fsc[qa];
        }
        // redistribute to O layout (q = lg*4 + r)
#pragma unroll
        for (int qa = 0; qa < 2; ++qa) {
          float fo[4];
#pragma unroll
          for (int r = 0; r < 4; ++r) fo[r] = __shfl(fsc[qa], lg * 4 + r);
#pragma unroll
          for (int fn = 0; fn < 8; ++fn)
#pragma unroll
            for (int r = 0; r < 4; ++r) O[qa][fn][r] *= fo[r];
        }
      }
      // exp2 + packed P write + per-lane partial sum
#pragma unroll
      for (int qa = 0; qa < 2; ++qa) {
        float ls = 0.f;
        int prow = qa * 16 + lr;
        int swz = (lr & 7) << 3;
#pragma unroll
        for (int fp = 0; fp < 4; ++fp) {
          float e0 = __builtin_amdgcn_exp2f(sacc[qa][fp][0] - mrow[qa]);
          float e1 = __builtin_amdgcn_exp2f(sacc[qa][fp][1] - mrow[qa]);
          float e2 = __builtin_amdgcn_exp2f(sacc[qa][fp][2] - mrow[qa]);
          float e3 = __builtin_amdgcn_exp2f(sacc[qa][fp][3] - mrow[qa]);
          ls += (e0 + e1) + (e2 + e3);
          unsigned lo = (unsigned)f2bf(e0) | ((unsigned)f2bf(e1) << 16);
          unsigned hi = (unsigned)f2bf(e2) | ((unsigned)f2bf(e3) << 16);
          uint2 pk; pk.x = lo; pk.y = hi;
          *reinterpret_cast<uint2*>(&Ps[w][prow][(fp * 16 + lg * 4) ^ swz]) = pk;
        }
        lrow[qa] += ls;
      }
      __builtin_amdgcn_s_setprio(1);
#pragma unroll
      for (int ks2 = 0; ks2 < 2; ++ks2) {
        s16x8 ap[2];
#pragma unroll
        for (int qa = 0; qa < 2; ++qa) {
          int prow = qa * 16 + lr;
          ap[qa] = *(const s16x8*)&Ps[w][prow][(ks2 * 32 + lg * 8) ^ ((lr & 7) << 3)];
        }
#pragma unroll
        for (int fn = 0; fn < 8; ++fn) {
          int vrow = fn * 16 + lr;
          s16x8 bv = *(const s16x8*)&Vs[c][vrow][(ks2 * 32 + lg * 8) ^ ((vrow & 7) << 3)];
#pragma unroll
          for (int qa = 0; qa < 2; ++qa)
            O[qa][fn] = __builtin_amdgcn_mfma_f32_16x16x32_bf16(ap[qa], bv, O[qa][fn], 0, 0, 0);
        }
      }
      __builtin_amdgcn_s_setprio(0);
    }
    __builtin_amdgcn_s_barrier();  // (b) all waves done reading buf c
  }

  // epilogue: finish the deferred cross-lane lrow reduction (once per block)
#pragma unroll
  for (int qa = 0; qa < 2; ++qa) {
    lrow[qa] += __shfl_xor(lrow[qa], 16);
    lrow[qa] += __shfl_xor(lrow[qa], 32);
  }
  // O rows are q = lg*4+r; lrow lives at lane&15 == q -> shfl remap
#pragma unroll
  for (int qa = 0; qa < 2; ++qa) {
    float inv = 1.0f / lrow[qa];
    float invq[4];
#pragma unroll
    for (int r = 0; r < 4; ++r) invq[r] = __shfl(inv, lg * 4 + r);
#pragma unroll
    for (int fn = 0; fn < 8; ++fn)
#pragma unroll
      for (int r = 0; r < 4; ++r) {
        size_t idx = (size_t)(b * 2048 + q0 + w * 32 + qa * 16 + lg * 4 + r) * 2048 +
                     h * 128 + fn * 16 + lr;
        AO[idx] = f2bf(O[qa][fn][r] * invq[r]);
      }
  }
}

extern "C" void kernel_launch(void* const* d_in, const int* in_sizes, int n_in,
                              void* d_out, int out_size, void* d_ws, size_t ws_size,
                              hipStream_t stream) {
  (void)in_sizes; (void)n_in; (void)out_size; (void)ws_size;
  const float* x = (const float*)d_in[0];
  const float* Wq = (const float*)d_in[1];
  const float* Wk = (const float*)d_in[2];
  const float* Wv = (const float*)d_in[3];
  const float* Wo = (const float*)d_in[4];
  const float* qw = (const float*)d_in[5];
  const float* kw = (const float*)d_in[6];
  float* out = (float*)d_out;

  char* ws = (char*)d_ws;
  size_t off = 0;
  auto alloc = [&](size_t bytes) {
    void* p = ws + off;
    off += (bytes + 255) & ~(size_t)255;
    return p;
  };
  ushort* xb = (ushort*)alloc((size_t)4096 * 2048 * 2);
  ushort* WqkvT = (ushort*)alloc((size_t)3072 * 2048 * 2);
  ushort* WoT = (ushort*)alloc((size_t)2048 * 2048 * 2);
  ushort* QKVraw = (ushort*)alloc((size_t)4096 * 3072 * 2);
  ushort* Kb = (ushort*)alloc((size_t)4096 * 512 * 2);
  ushort* Vt = (ushort*)alloc((size_t)4096 * 512 * 2);
  ushort* AO = (ushort*)alloc((size_t)4096 * 2048 * 2);
  float* rc = (float*)alloc((size_t)2048 * 64 * 4);
  float* rs = (float*)alloc((size_t)2048 * 64 * 4);

  preproc_kernel<<<12800, 256, 0, stream>>>(x, Wq, Wk, Wv, Wo, xb, WqkvT, WoT, rc, rs);
  gemm192_kernel<false><<<dim3(16, 16), 512, 0, stream>>>(xb, WqkvT, QKVraw, 4096, 3072, 2048);
  postqkv_kernel<<<4352, 256, 0, stream>>>(QKVraw, kw, Kb, Vt, rc, rs);
  attn_kernel<<<512, 256, 0, stream>>>(QKVraw, Kb, Vt, AO, rc, rs, qw);
  gemm256_kernel<true><<<dim3(16, 16), 512, 0, stream>>>(AO, WoT, out, 4096, 2048, 2048);
}

// Round 17
// 191.922 us; speedup vs baseline: 1.0012x; 1.0012x over previous
//
#include <hip/hip_runtime.h>

typedef __attribute__((ext_vector_type(4))) float f32x4;
typedef __attribute__((ext_vector_type(8))) short s16x8;

struct alignas(8) us4 { ushort x, y, z, w; };

__device__ __forceinline__ ushort f2bf(float f) {
  unsigned u = __builtin_bit_cast(unsigned, f);
  u += 0x7fffu + ((u >> 16) & 1u);
  return (ushort)(u >> 16);
}
__device__ __forceinline__ float bf2f(ushort h) {
  unsigned u = ((unsigned)h) << 16;
  return __builtin_bit_cast(float, u);
}

__device__ __forceinline__ void gload_lds16(const ushort* g, ushort* l) {
  __builtin_amdgcn_global_load_lds((const __attribute__((address_space(1))) unsigned int*)g,
                                   (__attribute__((address_space(3))) unsigned int*)l, 16, 0, 0);
}

// ---------------- merged preprocessing: cast + 4 weight transposes + rope tables --
__global__ __launch_bounds__(256) void preproc_kernel(
    const float* __restrict__ x, const float* __restrict__ Wq, const float* __restrict__ Wk,
    const float* __restrict__ Wv, const float* __restrict__ Wo,
    ushort* __restrict__ xb, ushort* __restrict__ WqkvT, ushort* __restrict__ WoT,
    float* __restrict__ rc, float* __restrict__ rs) {
  __shared__ float tile[32][33];
  int bid = blockIdx.x, tid = threadIdx.x;
  if (bid < 2048) {
    const int n4 = 4096 * 2048 / 4;
    for (int i = bid * 256 + tid; i < n4; i += 2048 * 256) {
      float4 v = reinterpret_cast<const float4*>(x)[i];
      us4 o;
      o.x = f2bf(v.x); o.y = f2bf(v.y); o.z = f2bf(v.z); o.w = f2bf(v.w);
      reinterpret_cast<us4*>(xb)[i] = o;
    }
  } else if (bid < 2560) {
    int t = (bid - 2048) * 4 + (tid >> 6), j = tid & 63;
    float inv = expf(-(float)j * (9.210340371976184f / 64.0f));
    float ang = (float)t * inv;
    float s, c;
    sincosf(ang, &s, &c);
    rc[t * 64 + j] = c;
    rs[t * 64 + j] = s;
  } else {
    int wid = bid - 2560;
    const float* src;
    ushort* dst;
    int C, bx, by;
    if (wid < 4096) { src = Wq; dst = WqkvT; C = 2048; bx = wid & 63; by = wid >> 6; }
    else if (wid < 5120) { int w2 = wid - 4096; src = Wk; dst = WqkvT + (size_t)2048 * 2048; C = 512; bx = w2 & 15; by = w2 >> 4; }
    else if (wid < 6144) { int w2 = wid - 5120; src = Wv; dst = WqkvT + (size_t)2560 * 2048; C = 512; bx = w2 & 15; by = w2 >> 4; }
    else { int w2 = wid - 6144; src = Wo; dst = WoT; C = 2048; bx = w2 & 63; by = w2 >> 6; }
    int c0 = bx * 32, r0 = by * 32;
    int tx = tid & 31, ty = tid >> 5;
#pragma unroll
    for (int i = 0; i < 4; ++i)
      tile[ty + i * 8][tx] = src[(size_t)(r0 + ty + i * 8) * C + c0 + tx];
    __syncthreads();
#pragma unroll
    for (int i = 0; i < 4; ++i)
      dst[(size_t)(c0 + ty + i * 8) * 2048 + r0 + tx] = f2bf(tile[tx][ty + i * 8]);
  }
}

// ---------------- merged post-QKV: K RMSNorm+RoPE and V transpose ----------------
__global__ __launch_bounds__(256) void postqkv_kernel(
    const ushort* __restrict__ qkv, const float* __restrict__ kw,
    ushort* __restrict__ Kb, ushort* __restrict__ vt,
    const float* __restrict__ rc, const float* __restrict__ rs) {
  __shared__ ushort tile[64][136];
  int bid = blockIdx.x, tid = threadIdx.x;
  if (bid < 4096) {
    int wv = tid >> 6, lane = tid & 63;
    int row = bid * 4 + wv;
    int token = row >> 2, head = row & 3;
    const ushort* p = qkv + (size_t)token * 3072 + 2048 + head * 128;
    float x1 = bf2f(p[lane]), x2 = bf2f(p[lane + 64]);
    float ss = x1 * x1 + x2 * x2;
#pragma unroll
    for (int m = 32; m > 0; m >>= 1) ss += __shfl_xor(ss, m);
    float r = rsqrtf(ss * (1.0f / 128.0f) + 1e-6f);
    float xn1 = x1 * r * kw[lane], xn2 = x2 * r * kw[lane + 64];
    int t = token & 2047;
    float c = rc[t * 64 + lane], s = rs[t * 64 + lane];
    ushort* o = Kb + (size_t)token * 512 + head * 128;
    o[lane] = f2bf(xn1 * c - xn2 * s);
    o[lane + 64] = f2bf(xn2 * c + xn1 * s);
  } else {
    int bx = bid - 4096;
    int st = bx & 31, kvh = (bx >> 5) & 3, b = bx >> 7;
    int s0 = st * 64;
#pragma unroll
    for (int p = 0; p < 4; ++p) {
      int idx = p * 2048 + tid * 8;
      int s = idx >> 7, d = idx & 127;
      *(s16x8*)&tile[s][d] =
          *(const s16x8*)&qkv[(size_t)(b * 2048 + s0 + s) * 3072 + 2560 + kvh * 128 + d];
    }
    __syncthreads();
#pragma unroll
    for (int p = 0; p < 4; ++p) {
      int idx = p * 2048 + tid * 8;
      int d = idx >> 6, s = idx & 63;
      s16x8 v;
#pragma unroll
      for (int u = 0; u < 8; ++u) v[u] = (short)tile[s + u][d];
      *(s16x8*)&vt[(size_t)((b * 4 + kvh) * 128 + d) * 2048 + s0 + s] = v;
    }
  }
}

// ---------------- bf16 MFMA GEMM, 256x192 tile, 2-slot dbuf, single barrier/tile --
// 16x16 = 256 blocks = one residency round on 256 CUs. 8 waves (2M x 4N),
// wave tile 128x48. stage(t+1) -> ds_read+MFMA(t) -> vmcnt(0) -> barrier.
template <bool OUTF32>
__global__ __launch_bounds__(512, 1) void gemm192_kernel(const ushort* __restrict__ A,
                                                         const ushort* __restrict__ Bt,
                                                         void* __restrict__ Cp,
                                                         int M, int N, int K) {
  __shared__ ushort As[2][256][64];  // 64 KB
  __shared__ ushort Bs[2][192][64];  // 48 KB
  int tid = threadIdx.x;
  int lane = tid & 63, wv = tid >> 6;  // 8 waves
  int wm = wv >> 2, wn = wv & 3;       // 2 x 4
  int lr = lane & 15, lg = lane >> 4;
  int nwg = gridDim.x * gridDim.y;
  int flat = blockIdx.y * gridDim.x + blockIdx.x;
  int swz = (flat & 7) * (nwg >> 3) + (flat >> 3);
  int bx = swz % gridDim.x, by = swz / gridDim.x;
  int m0 = by * 256, n0 = bx * 192;
  int srow8 = lane >> 3;
  int gcol = ((lane & 7) * 8) ^ (srow8 << 3);
  int nt = K >> 6;

  const ushort* Abase = A + (size_t)m0 * K;
  const ushort* Bbase = Bt + (size_t)n0 * K;

  auto stage = [&](int slot, int t) {
#pragma unroll
    for (int p = 0; p < 4; ++p) {
      int r0 = wv * 32 + p * 8;
      gload_lds16(&Abase[(size_t)(r0 + srow8) * K + t * 64 + gcol], &As[slot][r0][0]);
    }
#pragma unroll
    for (int p = 0; p < 3; ++p) {
      int r0 = wv * 24 + p * 8;
      gload_lds16(&Bbase[(size_t)(r0 + srow8) * K + t * 64 + gcol], &Bs[slot][r0][0]);
    }
  };

  // prologue: tile 0 staged and certified resident
  stage(0, 0);
  asm volatile("s_waitcnt vmcnt(0)" ::: "memory");
  __builtin_amdgcn_s_barrier();

  f32x4 acc[8][3] = {};
  int arow[8], aswz[8], brow[3], bswz[3];
#pragma unroll
  for (int i = 0; i < 8; ++i) {
    arow[i] = wm * 128 + i * 16 + lr;
    aswz[i] = (arow[i] & 7) << 3;
  }
#pragma unroll
  for (int j = 0; j < 3; ++j) {
    brow[j] = wn * 48 + j * 16 + lr;
    bswz[j] = (brow[j] & 7) << 3;
  }

  for (int t = 0; t < nt; ++t) {
    int c = t & 1;
    bool pf = (t + 1) < nt;
    if (pf) stage(c ^ 1, t + 1);   // issue next-tile loads into the other slot
#pragma unroll
    for (int ks = 0; ks < 2; ++ks) {
      s16x8 a[8], b[3];
#pragma unroll
      for (int i = 0; i < 8; ++i)
        a[i] = *(const s16x8*)&As[c][arow[i]][(ks * 32 + lg * 8) ^ aswz[i]];
#pragma unroll
      for (int j = 0; j < 3; ++j)
        b[j] = *(const s16x8*)&Bs[c][brow[j]][(ks * 32 + lg * 8) ^ bswz[j]];
      __builtin_amdgcn_s_setprio(1);
#pragma unroll
      for (int i = 0; i < 8; ++i)
#pragma unroll
        for (int j = 0; j < 3; ++j)
          acc[i][j] = __builtin_amdgcn_mfma_f32_16x16x32_bf16(a[i], b[j], acc[i][j], 0, 0, 0);
      __builtin_amdgcn_s_setprio(0);
    }
    if (pf) {
      asm volatile("s_waitcnt vmcnt(0)" ::: "memory");  // t+1 drained (covered by MFMA)
      __builtin_amdgcn_s_barrier();                     // joint certify: data in + slot free
    }
  }
#pragma unroll
  for (int i = 0; i < 8; ++i)
#pragma unroll
    for (int j = 0; j < 3; ++j) {
      int row = m0 + wm * 128 + i * 16 + lg * 4;
      int col = n0 + wn * 48 + j * 16 + lr;
#pragma unroll
      for (int r = 0; r < 4; ++r) {
        float v = acc[i][j][r];
        if (OUTF32)
          reinterpret_cast<float*>(Cp)[(size_t)(row + r) * N + col] = v;
        else
          reinterpret_cast<ushort*>(Cp)[(size_t)(row + r) * N + col] = f2bf(v);
      }
    }
}

// ---------------- bf16 MFMA GEMM, 256x128 tile, 3-slot pipelined (proj) ----------
template <bool OUTF32>
__global__ __launch_bounds__(512, 2) void gemm256_kernel(const ushort* __restrict__ A,
                                                         const ushort* __restrict__ Bt,
                                                         void* __restrict__ Cp,
                                                         int M, int N, int K) {
  __shared__ ushort As[3][256][64];  // 96 KB
  __shared__ ushort Bs[3][128][64];  // 48 KB
  int tid = threadIdx.x;
  int lane = tid & 63, wv = tid >> 6;  // 8 waves
  int wm = wv >> 1, wn = wv & 1;       // 4 x 2
  int lr = lane & 15, lg = lane >> 4;
  int nwg = gridDim.x * gridDim.y;
  int flat = blockIdx.y * gridDim.x + blockIdx.x;
  int swz = (flat & 7) * (nwg >> 3) + (flat >> 3);
  int bx = swz % gridDim.x, by = swz / gridDim.x;
  int m0 = by * 256, n0 = bx * 128;
  int srow8 = lane >> 3;
  int gcol = ((lane & 7) * 8) ^ (srow8 << 3);
  int nt = K >> 6;

  const ushort* Abase = A + (size_t)m0 * K;
  const ushort* Bbase = Bt + (size_t)n0 * K;

  auto stageA = [&](int slot, int t, int p) {
    int r0 = (wv * 4 + p) * 8;
    gload_lds16(&Abase[(size_t)(r0 + srow8) * K + t * 64 + gcol], &As[slot][r0][0]);
  };
  auto stageB = [&](int slot, int t, int p) {
    int r0 = (wv * 2 + p) * 8;
    gload_lds16(&Bbase[(size_t)(r0 + srow8) * K + t * 64 + gcol], &Bs[slot][r0][0]);
  };

  stageA(0, 0, 0); stageA(0, 0, 1); stageB(0, 0, 0);
  stageA(0, 0, 2); stageA(0, 0, 3); stageB(0, 0, 1);
  stageA(1, 1, 0); stageA(1, 1, 1); stageB(1, 1, 0);
  stageA(1, 1, 2); stageA(1, 1, 3); stageB(1, 1, 1);

  f32x4 acc[4][4] = {};
  int arow[4], brow[4], aswz[4], bswz[4];
#pragma unroll
  for (int i = 0; i < 4; ++i) {
    arow[i] = wm * 64 + i * 16 + lr;
    aswz[i] = (arow[i] & 7) << 3;
    brow[i] = wn * 64 + i * 16 + lr;
    bswz[i] = (brow[i] & 7) << 3;
  }

  for (int t = 0; t < nt; ++t) {
    int cur = t % 3, pf = (t + 2) % 3;
    if (t + 1 < nt) {
      asm volatile("s_waitcnt vmcnt(6)" ::: "memory");
    } else {
      asm volatile("s_waitcnt vmcnt(0)" ::: "memory");
    }
    __builtin_amdgcn_s_barrier();
    bool do_pf = (t + 2) < nt;
    {
      s16x8 a[4], b[4];
#pragma unroll
      for (int i = 0; i < 4; ++i) a[i] = *(const s16x8*)&As[cur][arow[i]][(lg * 8) ^ aswz[i]];
#pragma unroll
      for (int j = 0; j < 4; ++j) b[j] = *(const s16x8*)&Bs[cur][brow[j]][(lg * 8) ^ bswz[j]];
      if (do_pf) { stageA(pf, t + 2, 0); stageA(pf, t + 2, 1); stageB(pf, t + 2, 0); }
      __builtin_amdgcn_s_setprio(1);
#pragma unroll
      for (int i = 0; i < 4; ++i)
#pragma unroll
        for (int j = 0; j < 4; ++j)
          acc[i][j] = __builtin_amdgcn_mfma_f32_16x16x32_bf16(a[i], b[j], acc[i][j], 0, 0, 0);
      __builtin_amdgcn_s_setprio(0);
    }
    {
      s16x8 a[4], b[4];
#pragma unroll
      for (int i = 0; i < 4; ++i) a[i] = *(const s16x8*)&As[cur][arow[i]][(32 + lg * 8) ^ aswz[i]];
#pragma unroll
      for (int j = 0; j < 4; ++j) b[j] = *(const s16x8*)&Bs[cur][brow[j]][(32 + lg * 8) ^ bswz[j]];
      if (do_pf) { stageA(pf, t + 2, 2); stageA(pf, t + 2, 3); stageB(pf, t + 2, 1); }
      __builtin_amdgcn_s_setprio(1);
#pragma unroll
      for (int i = 0; i < 4; ++i)
#pragma unroll
        for (int j = 0; j < 4; ++j)
          acc[i][j] = __builtin_amdgcn_mfma_f32_16x16x32_bf16(a[i], b[j], acc[i][j], 0, 0, 0);
      __builtin_amdgcn_s_setprio(0);
    }
  }
#pragma unroll
  for (int i = 0; i < 4; ++i)
#pragma unroll
    for (int j = 0; j < 4; ++j) {
      int row = m0 + wm * 64 + i * 16 + lg * 4;
      int col = n0 + wn * 64 + j * 16 + lr;
#pragma unroll
      for (int r = 0; r < 4; ++r) {
        float v = acc[i][j][r];
        if (OUTF32)
          reinterpret_cast<float*>(Cp)[(size_t)(row + r) * N + col] = v;
        else
          reinterpret_cast<ushort*>(Cp)[(size_t)(row + r) * N + col] = f2bf(v);
      }
    }
}

// ---------------- causal GQA flash attention (r9 proven) ----------------
__global__ __launch_bounds__(256, 2) void attn_kernel(const ushort* __restrict__ QKV,
                                                      const ushort* __restrict__ Kn,
                                                      const ushort* __restrict__ Vt,
                                                      ushort* __restrict__ AO,
                                                      const float* __restrict__ rc,
                                                      const float* __restrict__ rs,
                                                      const float* __restrict__ qw) {
  __shared__ ushort Ks[2][64][128];   // 32 KB
  __shared__ ushort Vs[2][128][64];   // 32 KB
  __shared__ ushort Ps[4][32][64];    // 16 KB
  int bxi = blockIdx.x;
  int g = bxi >> 5, bh = bxi & 31;
  int qt = (g < 8) ? (15 - g) : (g - 8);  // pair long+short on each CU
  int b = bh >> 4, h = bh & 15, kvh = h >> 2;
  int q0 = qt * 128;
  int nt = 2 * qt + 2;
  int tid = threadIdx.x, lane = tid & 63, w = tid >> 6;
  int lr = lane & 15, lg = lane >> 4;

  int ksrow = lane >> 4, kscol = (lane & 15) * 8;
  int vsrow = lane >> 3, vscol = (lane & 7) * 8;

  auto stage = [&](int c, int t) {
    int p0 = t * 64;
#pragma unroll
    for (int p = 0; p < 4; ++p) {
      int r0 = w * 16 + p * 4;
      int row = r0 + ksrow;
      int gc = kscol ^ ((row & 7) << 3);
      gload_lds16(&Kn[(size_t)(b * 2048 + p0 + row) * 512 + kvh * 128 + gc], &Ks[c][r0][0]);
    }
#pragma unroll
    for (int p = 0; p < 4; ++p) {
      int r0 = w * 32 + p * 8;
      int row = r0 + vsrow;
      int gc = vscol ^ ((row & 7) << 3);
      gload_lds16(&Vt[(size_t)((b * 4 + kvh) * 128 + row) * 2048 + p0 + gc], &Vs[c][r0][0]);
    }
  };

  stage(0, 0);  // tile 0 in flight — overlaps the Q-build below

  // ---- Q build: inline RMSNorm + RoPE + QSCALE ----
  const float QSCALE = 0.12751744f;  // log2e / sqrt(128)
  s16x8 qf[2][4];
#pragma unroll
  for (int qa = 0; qa < 2; ++qa) {
    int t_tok = q0 + w * 32 + qa * 16 + lr;
    const ushort* qp = QKV + (size_t)(b * 2048 + t_tok) * 3072 + h * 128;
    float xv[4][8];
    float ss = 0.f;
#pragma unroll
    for (int ks = 0; ks < 4; ++ks) {
      s16x8 raw = *(const s16x8*)&qp[ks * 32 + lg * 8];
#pragma unroll
      for (int j = 0; j < 8; ++j) {
        float x = bf2f((ushort)raw[j]);
        xv[ks][j] = x;
        ss += x * x;
      }
    }
    ss += __shfl_xor(ss, 16);
    ss += __shfl_xor(ss, 32);
    float rms = rsqrtf(ss * (1.0f / 128.0f) + 1e-6f);
#pragma unroll
    for (int ks = 0; ks < 2; ++ks) {
      int dbase = ks * 32 + lg * 8;
      float cc[8], sn[8], w1[8], w2[8];
      *(float4*)&cc[0] = *(const float4*)&rc[(size_t)t_tok * 64 + dbase];
      *(float4*)&cc[4] = *(const float4*)&rc[(size_t)t_tok * 64 + dbase + 4];
      *(float4*)&sn[0] = *(const float4*)&rs[(size_t)t_tok * 64 + dbase];
      *(float4*)&sn[4] = *(const float4*)&rs[(size_t)t_tok * 64 + dbase + 4];
      *(float4*)&w1[0] = *(const float4*)&qw[dbase];
      *(float4*)&w1[4] = *(const float4*)&qw[dbase + 4];
      *(float4*)&w2[0] = *(const float4*)&qw[dbase + 64];
      *(float4*)&w2[4] = *(const float4*)&qw[dbase + 68];
      s16x8 o1, o2;
#pragma unroll
      for (int j = 0; j < 8; ++j) {
        float x1 = xv[ks][j] * rms * w1[j];
        float x2 = xv[ks + 2][j] * rms * w2[j];
        o1[j] = (short)f2bf((x1 * cc[j] - x2 * sn[j]) * QSCALE);
        o2[j] = (short)f2bf((x2 * cc[j] + x1 * sn[j]) * QSCALE);
      }
      qf[qa][ks] = o1;
      qf[qa][ks + 2] = o2;
    }
  }

  f32x4 O[2][8] = {};
  float mrow[2] = {-1e30f, -1e30f};  // wave-row-uniform running max (log2 domain)
  float lrow[2] = {0.f, 0.f};        // per-lane partial sum over this lane's k-slice

  for (int t = 0; t < nt; ++t) {
    int c = t & 1;
    if (t + 1 < nt) {
      stage(c ^ 1, t + 1);                               // prefetch next tile
      asm volatile("s_waitcnt vmcnt(8)" ::: "memory");   // tile t's 8 loads done
    } else {
      asm volatile("s_waitcnt vmcnt(0)" ::: "memory");
    }
    __builtin_amdgcn_s_barrier();                        // (a) tile t visible

    bool skip = (t == 2 * qt + 1) && (w < 2);            // fully-masked wave-tile
    if (!skip) {
      // SWAPPED: sacc[qa][fp] = S^T tile: lane holds q=lane&15, k=fp*16+lg*4+r
      f32x4 sacc[2][4] = {};
      __builtin_amdgcn_s_setprio(1);
#pragma unroll
      for (int ks = 0; ks < 4; ++ks) {
        s16x8 bk[4];
#pragma unroll
        for (int fp = 0; fp < 4; ++fp) {
          int kr = fp * 16 + lr;
          bk[fp] = *(const s16x8*)&Ks[c][kr][(ks * 32 + lg * 8) ^ ((kr & 7) << 3)];
        }
#pragma unroll
        for (int qa = 0; qa < 2; ++qa)
#pragma unroll
          for (int fp = 0; fp < 4; ++fp)
            sacc[qa][fp] = __builtin_amdgcn_mfma_f32_16x16x32_bf16(bk[fp], qf[qa][ks], sacc[qa][fp], 0, 0, 0);
      }
      __builtin_amdgcn_s_setprio(0);

      // causal mask (only tiles straddling the diagonal)
      if (t >= 2 * qt) {
        int p0 = t * 64;
#pragma unroll
        for (int qa = 0; qa < 2; ++qa)
#pragma unroll
          for (int fp = 0; fp < 4; ++fp)
#pragma unroll
            for (int r = 0; r < 4; ++r) {
              int qg = q0 + w * 32 + qa * 16 + lr;
              int pg = p0 + fp * 16 + lg * 4 + r;
              if (pg > qg) sacc[qa][fp][r] = -1e30f;
            }
      }

      // in-lane row max (16 values, tree)
      float pml[2];
#pragma unroll
      for (int qa = 0; qa < 2; ++qa) {
        float m0 = fmaxf(fmaxf(sacc[qa][0][0], sacc[qa][0][1]), fmaxf(sacc[qa][0][2], sacc[qa][0][3]));
        float m1 = fmaxf(fmaxf(sacc[qa][1][0], sacc[qa][1][1]), fmaxf(sacc[qa][1][2], sacc[qa][1][3]));
        float m2 = fmaxf(fmaxf(sacc[qa][2][0], sacc[qa][2][1]), fmaxf(sacc[qa][2][2], sacc[qa][2][3]));
        float m3 = fmaxf(fmaxf(sacc[qa][3][0], sacc[qa][3][1]), fmaxf(sacc[qa][3][2], sacc[qa][3][3]));
        pml[qa] = fmaxf(fmaxf(m0, m1), fmaxf(m2, m3));
      }
      // defer gate on in-lane max: pm_full > thr  <=>  any lane's pml > thr
      bool need = (pml[0] > mrow[0] + 8.0f) | (pml[1] > mrow[1] + 8.0f);
      if (__any((int)need)) {
        float fsc[2];
#pragma unroll
        for (int qa = 0; qa < 2; ++qa) {
          float pm = fmaxf(pml[qa], __shfl_xor(pml[qa], 16));
          pm = fmaxf(pm, __shfl_xor(pm, 32));
          float mn = fmaxf(mrow[qa], pm);
          fsc[qa] = __builtin_amdgcn_exp2f(mrow[qa] - mn);
          mrow[qa] = mn;
          lrow[qa] *= fsc[qa];
        }
        // redistribute to O layout (q = lg*4 + r)
#pragma unroll
        for (int qa = 0; qa < 2; ++qa) {
          float fo[4];
#pragma unroll
          for (int r = 0; r < 4; ++r) fo[r] = __shfl(fsc[qa], lg * 4 + r);
#pragma unroll
          for (int fn = 0; fn < 8; ++fn)
#pragma unroll
            for (int r = 0; r < 4; ++r) O[qa][fn][r] *= fo[r];
        }
      }
      // exp2 + packed P write + per-lane partial sum
#pragma unroll
      for (int qa = 0; qa < 2; ++qa) {
        float ls = 0.f;
        int prow = qa * 16 + lr;
        int swz = (lr & 7) << 3;
#pragma unroll
        for (int fp = 0; fp < 4; ++fp) {
          float e0 = __builtin_amdgcn_exp2f(sacc[qa][fp][0] - mrow[qa]);
          float e1 = __builtin_amdgcn_exp2f(sacc[qa][fp][1] - mrow[qa]);
          float e2 = __builtin_amdgcn_exp2f(sacc[qa][fp][2] - mrow[qa]);
          float e3 = __builtin_amdgcn_exp2f(sacc[qa][fp][3] - mrow[qa]);
          ls += (e0 + e1) + (e2 + e3);
          unsigned lo = (unsigned)f2bf(e0) | ((unsigned)f2bf(e1) << 16);
          unsigned hi = (unsigned)f2bf(e2) | ((unsigned)f2bf(e3) << 16);
          uint2 pk; pk.x = lo; pk.y = hi;
          *reinterpret_cast<uint2*>(&Ps[w][prow][(fp * 16 + lg * 4) ^ swz]) = pk;
        }
        lrow[qa] += ls;
      }
      __builtin_amdgcn_s_setprio(1);
#pragma unroll
      for (int ks2 = 0; ks2 < 2; ++ks2) {
        s16x8 ap[2];
#pragma unroll
        for (int qa = 0; qa < 2; ++qa) {
          int prow = qa * 16 + lr;
          ap[qa] = *(const s16x8*)&Ps[w][prow][(ks2 * 32 + lg * 8) ^ ((lr & 7) << 3)];
        }
#pragma unroll
        for (int fn = 0; fn < 8; ++fn) {
          int vrow = fn * 16 + lr;
          s16x8 bv = *(const s16x8*)&Vs[c][vrow][(ks2 * 32 + lg * 8) ^ ((vrow & 7) << 3)];
#pragma unroll
          for (int qa = 0; qa < 2; ++qa)
            O[qa][fn] = __builtin_amdgcn_mfma_f32_16x16x32_bf16(ap[qa], bv, O[qa][fn], 0, 0, 0);
        }
      }
      __builtin_amdgcn_s_setprio(0);
    }
    __builtin_amdgcn_s_barrier();  // (b) all waves done reading buf c
  }

  // epilogue: finish the deferred cross-lane lrow reduction (once per block)
#pragma unroll
  for (int qa = 0; qa < 2; ++qa) {
    lrow[qa] += __shfl_xor(lrow[qa], 16);
    lrow[qa] += __shfl_xor(lrow[qa], 32);
  }
  // O rows are q = lg*4+r; lrow lives at lane&15 == q -> shfl remap
#pragma unroll
  for (int qa = 0; qa < 2; ++qa) {
    float inv = 1.0f / lrow[qa];
    float invq[4];
#pragma unroll
    for (int r = 0; r < 4; ++r) invq[r] = __shfl(inv, lg * 4 + r);
#pragma unroll
    for (int fn = 0; fn < 8; ++fn)
#pragma unroll
      for (int r = 0; r < 4; ++r) {
        size_t idx = (size_t)(b * 2048 + q0 + w * 32 + qa * 16 + lg * 4 + r) * 2048 +
                     h * 128 + fn * 16 + lr;
        AO[idx] = f2bf(O[qa][fn][r] * invq[r]);
      }
  }
}

extern "C" void kernel_launch(void* const* d_in, const int* in_sizes, int n_in,
                              void* d_out, int out_size, void* d_ws, size_t ws_size,
                              hipStream_t stream) {
  (void)in_sizes; (void)n_in; (void)out_size; (void)ws_size;
  const float* x = (const float*)d_in[0];
  const float* Wq = (const float*)d_in[1];
  const float* Wk = (const float*)d_in[2];
  const float* Wv = (const float*)d_in[3];
  const float* Wo = (const float*)d_in[4];
  const float* qw = (const float*)d_in[5];
  const float* kw = (const float*)d_in[6];
  float* out = (float*)d_out;

  char* ws = (char*)d_ws;
  size_t off = 0;
  auto alloc = [&](size_t bytes) {
    void* p = ws + off;
    off += (bytes + 255) & ~(size_t)255;
    return p;
  };
  ushort* xb = (ushort*)alloc((size_t)4096 * 2048 * 2);
  ushort* WqkvT = (ushort*)alloc((size_t)3072 * 2048 * 2);
  ushort* WoT = (ushort*)alloc((size_t)2048 * 2048 * 2);
  ushort* QKVraw = (ushort*)alloc((size_t)4096 * 3072 * 2);
  ushort* Kb = (ushort*)alloc((size_t)4096 * 512 * 2);
  ushort* Vt = (ushort*)alloc((size_t)4096 * 512 * 2);
  ushort* AO = (ushort*)alloc((size_t)4096 * 2048 * 2);
  float* rc = (float*)alloc((size_t)2048 * 64 * 4);
  float* rs = (float*)alloc((size_t)2048 * 64 * 4);

  preproc_kernel<<<12800, 256, 0, stream>>>(x, Wq, Wk, Wv, Wo, xb, WqkvT, WoT, rc, rs);
  gemm192_kernel<false><<<dim3(16, 16), 512, 0, stream>>>(xb, WqkvT, QKVraw, 4096, 3072, 2048);
  postqkv_kernel<<<4352, 256, 0, stream>>>(QKVraw, kw, Kb, Vt, rc, rs);
  attn_kernel<<<512, 256, 0, stream>>>(QKVraw, Kb, Vt, AO, rc, rs, qw);
  gemm256_kernel<true><<<dim3(16, 16), 512, 0, stream>>>(AO, WoT, out, 4096, 2048, 2048);
}